// Round 8
// baseline (237.894 us; speedup 1.0000x reference)
//
#include <hip/hip_runtime.h>
#include <hip/hip_bf16.h>

#define PP     512
#define KK     64
#define BB     32
#define LLEN   2048
#define TPOS   64           // output positions per chunk
#define SROWS  74           // 64 positions + 2*5 conv halo
#define NCHUNK (LLEN / TPOS)   // 32 chunks per batch
#define CPB    2            // chunks per block (register-carried pipeline)

typedef __attribute__((ext_vector_type(8)))  short short8;
typedef __attribute__((ext_vector_type(16))) float float16;

__device__ inline unsigned int pack_bf2(float lo, float hi) {
    __hip_bfloat162 h = __float22bfloat162_rn(make_float2(lo, hi));
    unsigned int u;
    __builtin_memcpy(&u, &h, 4);
    return u;   // low 16 = lo, high 16 = hi
}
__device__ inline float bf_lo(unsigned int v) { return __uint_as_float(v << 16); }
__device__ inline float bf_hi(unsigned int v) { return __uint_as_float(v & 0xffff0000u); }

// ---------------------------------------------------------------------------
// K1: unified B-operand fragments, 128 cols: n<64 -> l_hat[n], n>=64 -> f2w[n-64].
// Bu4[f*128 + n] = 8 bf16 of src[n][8f..8f+7] (f = 0..63).  (unchanged)
// ---------------------------------------------------------------------------
__global__ void k1_prep(const float* __restrict__ C, const float* __restrict__ f2w,
                        ushort* __restrict__ Bu) {
    const int n = blockIdx.x;            // 0..127
    const float* src = (n < 64) ? (C + n * PP) : (f2w + (n - 64) * PP);
    const int t = threadIdx.x;
    float v0 = src[t];
    float v1 = src[t + 256];
    __shared__ float red[256];
    red[t] = v0 * v0 + v1 * v1;
    __syncthreads();
    for (int s = 128; s > 0; s >>= 1) {
        if (t < s) red[t] += red[t + s];
        __syncthreads();
    }
    const float inv = (n < 64) ? rsqrtf(red[0]) : 1.f;
    Bu[(((t >> 3)       * 128 + n) << 3) + (t & 7)] = (ushort)(pack_bf2(v0 * inv, 0.f) & 0xffffu);
    Bu[((((t + 256) >> 3)) * 128 + n) * 8 + (t & 7)] = (ushort)(pack_bf2(v1 * inv, 0.f) & 0xffffu);
}

// ---------------------------------------------------------------------------
// K2 fused: r5's winning config (TPOS=64, 512 thr, 76KB LDS, 2 blocks/CU,
// VGPR<=128) + register-carried chunk pipeline (CPB=2, SINGLE LDS buffer):
// ISSUE chunk i+1's gathers right after chunk i's staging barrier; loads fly
// across MFMA + full epilogue (covers HBM latency); PACK at next loop top
// into the same (dead) sA. Per-thread token loads (no stok barrier).
// Round-7 lesson: pipelining needs co-residency; regs are the 2nd buffer.
// Output: pool[chunk][0..63]=partial, [64]=chunk max, [65]=chunk expsum.
// ---------------------------------------------------------------------------
__launch_bounds__(512, 4)   // 4 waves/EU -> 2 blocks/CU; VGPR cap 128
__global__ void k2_fused(const int* __restrict__ x, const float* __restrict__ V,
                         const uint4* __restrict__ Bu4,
                         const float* __restrict__ f1w, const float* __restrict__ f1b,
                         float* __restrict__ pool) {
    __shared__ uint4 sA[SROWS * 64];     // 75776 B; epilogue scratch aliases it
    __shared__ float rnorm[SROWS];
    __shared__ float smv[TPOS];
    __shared__ float sp[TPOS];
    __shared__ float sscal[2];

    const int tid  = threadIdx.x;
    const int lane = tid & 63;
    const int wv   = tid >> 6;           // 0..7
    const int l31  = lane & 31;
    const int chunk0 = blockIdx.x * CPB; // 2 consecutive chunks (same batch: chunk0 even)

    // staging geometry: main rows 0..63 by all 512 (8 thr/row, 16 float4);
    // halo rows 64..73 by tid 352..511 (16 thr/row, 8 float4)
    const int o   = tid & 7;
    const int r   = tid >> 3;
    const int ht  = tid - 352;
    const int h16 = ht & 15;
    const int rh  = 64 + (ht >> 4);

    float4 pa[8], pb[8], ph[8];

    // MFMA tile assignment (5 waves): cos staged-rows {0-31,32-63,42-73},
    // E2 staged-rows {5-36,37-68}
    const int rowBase = (wv == 0) ? 0 : (wv == 1) ? 32 : (wv == 2) ? 42
                      : (wv == 3) ? 5 : 37;
    const int cc = lane >> 5;

    // epilogue constants
    float w[11];
#pragma unroll
    for (int t = 0; t < 11; ++t) w[t] = f1w[t];
    const int j = l31;
    const int h = tid >> 5;                              // 0..15
    const float bias0 = f1b[j], bias1 = f1b[j + 32];

    auto ISSUE = [&](int chunk) {
        const int bb = chunk >> 5;
        const int l0c = (chunk & 31) * TPOS;
        const int gl  = min(max(l0c - 5 + r, 0), LLEN - 1);
        const int tok = x[bb * LLEN + gl];
        const float4* f4 = (const float4*)(V + (size_t)tok * PP);
#pragma unroll
        for (int g = 0; g < 8; ++g) pa[g] = f4[o + g * 8];
#pragma unroll
        for (int g = 0; g < 8; ++g) pb[g] = f4[o + (g + 8) * 8];
        if (ht >= 0) {
            const int glh  = min(max(l0c - 5 + rh, 0), LLEN - 1);
            const int tokh = x[bb * LLEN + glh];
            const float4* f4h = (const float4*)(V + (size_t)tokh * PP);
#pragma unroll
            for (int g = 0; g < 8; ++g) ph[g] = f4h[h16 + g * 16];
        }
    };
    auto PACK = [&]() {
        const int swzr = r & 7;
        float nrm = 0.f;
#pragma unroll
        for (int g = 0; g < 8; ++g) {
            const float4 a = pa[g];
            nrm = fmaf(a.x, a.x, fmaf(a.y, a.y, fmaf(a.z, a.z, fmaf(a.w, a.w, nrm))));
            uint2 w2; w2.x = pack_bf2(a.x, a.y); w2.y = pack_bf2(a.z, a.w);
            const int f = g * 4 + (o >> 1);
            ((uint2*)&sA[r * 64 + (f ^ swzr)])[o & 1] = w2;
        }
#pragma unroll
        for (int g = 0; g < 8; ++g) {
            const float4 a = pb[g];
            nrm = fmaf(a.x, a.x, fmaf(a.y, a.y, fmaf(a.z, a.z, fmaf(a.w, a.w, nrm))));
            uint2 w2; w2.x = pack_bf2(a.x, a.y); w2.y = pack_bf2(a.z, a.w);
            const int f = (g + 8) * 4 + (o >> 1);
            ((uint2*)&sA[r * 64 + (f ^ swzr)])[o & 1] = w2;
        }
        nrm += __shfl_xor(nrm, 1, 64);
        nrm += __shfl_xor(nrm, 2, 64);
        nrm += __shfl_xor(nrm, 4, 64);
        if (o == 0) rnorm[r] = rsqrtf(nrm);
        if (ht >= 0) {
            const int swzh = rh & 7;
            float nh2 = 0.f;
#pragma unroll
            for (int g = 0; g < 8; ++g) {
                const float4 a = ph[g];
                nh2 = fmaf(a.x, a.x, fmaf(a.y, a.y, fmaf(a.z, a.z, fmaf(a.w, a.w, nh2))));
                uint2 w2; w2.x = pack_bf2(a.x, a.y); w2.y = pack_bf2(a.z, a.w);
                const int f = g * 8 + (h16 >> 1);
                ((uint2*)&sA[rh * 64 + (f ^ swzh)])[h16 & 1] = w2;
            }
            nh2 += __shfl_xor(nh2, 1, 64);
            nh2 += __shfl_xor(nh2, 2, 64);
            nh2 += __shfl_xor(nh2, 4, 64);
            nh2 += __shfl_xor(nh2, 8, 64);
            if (h16 == 0) rnorm[rh] = rsqrtf(nh2);
        }
    };

    ISSUE(chunk0);    // prologue: first chunk's gather (exposed)

#pragma unroll
    for (int i = 0; i < CPB; ++i) {
        const int chunk = chunk0 + i;
        const int l0 = (chunk & 31) * TPOS;

        PACK();                               // consume in-flight loads -> sA
        __syncthreads();                      // sA staged

        if (i + 1 < CPB) ISSUE(chunk + 1);    // next gathers fly across MFMA+epilogue
        __builtin_amdgcn_sched_barrier(0);    // pin loads before MFMA cluster

        // ---- MFMA: 5 wave-tiles of 32 rows x 64 cols ----
        float16 c0, c1;
#pragma unroll
        for (int k = 0; k < 16; ++k) { c0[k] = 0.f; c1[k] = 0.f; }
        if (wv < 5) {
            const int nh    = (wv < 3) ? 0 : 64;   // cos cols 0-63 / E2 cols 64-127
            const int row   = rowBase + l31;
            const int abase = row * 64;
            const int aswz  = row & 7;
#pragma unroll 8
            for (int ks = 0; ks < 32; ++ks) {
                const int ff = ks * 2 + cc;
                const uint4 av = sA[abase + (ff ^ aswz)];
                const uint4 b0 = Bu4[ff * 128 + nh + l31];
                const uint4 b1 = Bu4[ff * 128 + nh + 32 + l31];
                short8 a8, t0, t1;
                __builtin_memcpy(&a8, &av, 16);
                __builtin_memcpy(&t0, &b0, 16);
                __builtin_memcpy(&t1, &b1, 16);
                c0 = __builtin_amdgcn_mfma_f32_32x32x16_bf16(a8, t0, c0, 0, 0, 0);
                c1 = __builtin_amdgcn_mfma_f32_32x32x16_bf16(a8, t1, c1, 0, 0, 0);
            }
        }
        __builtin_amdgcn_sched_barrier(0);
        __syncthreads();                      // MFMA reads of sA done -> alias ok

        // ---- epilogue: scratch aliases dead sA ----
        unsigned int* G32 = (unsigned int*)sA;             // [74][32] pairs: 9472 B
        float*        E2s = (float*)((char*)sA + 10240);   // [64][64] f32
        float*        sred = (float*)((char*)sA + 28672);  // [16][64] f32
        if (wv < 3) {                                       // cos waves
#pragma unroll
            for (int reg = 0; reg < 16; ++reg) {
                const int rr  = (reg & 3) + 8 * (reg >> 2) + 4 * cc;
                const int row = rowBase + rr;
                if (wv == 2 && row < 64) continue;          // wv1 owns overlap rows
                const int gl = l0 - 5 + row;
                unsigned int vpk = 0u;
                if (gl >= 0 && gl < LLEN) {
                    const float rn = rnorm[row];
                    vpk = pack_bf2(c0[reg] * rn, c1[reg] * rn);
                }
                G32[row * 32 + l31] = vpk;
            }
        } else if (wv < 5) {                                // E2 waves
#pragma unroll
            for (int reg = 0; reg < 16; ++reg) {
                const int rr = (reg & 3) + 8 * (reg >> 2) + 4 * cc;
                const int oo = rowBase - 5 + rr;            // 0..63
                E2s[oo * 64 + l31]      = c0[reg];
                E2s[oo * 64 + 32 + l31] = c1[reg];
            }
        }
        __syncthreads();

        // ---- conv(11) + relu + max over k ----
#pragma unroll
        for (int it = 0; it < 4; ++it) {
            const int oo = it * 16 + h;                     // output row 0..63
            float u0 = 0.f, u1 = 0.f;
#pragma unroll
            for (int tap = 0; tap < 11; ++tap) {
                const unsigned int v = G32[(oo + tap) * 32 + j];
                u0 = fmaf(bf_lo(v), w[tap], u0);
                u1 = fmaf(bf_hi(v), w[tap], u1);
            }
            float m = fmaxf(fmaxf(u0 + bias0, 0.f), fmaxf(u1 + bias1, 0.f));
#pragma unroll
            for (int off = 16; off > 0; off >>= 1)
                m = fmaxf(m, __shfl_xor(m, off, 64));       // reduce 32-lane half
            if (j == 0) smv[oo] = m;
        }
        __syncthreads();

        // ---- chunk softmax partials ----
        if (tid < 64) {
            float v = smv[tid];
#pragma unroll
            for (int off = 32; off > 0; off >>= 1)
                v = fmaxf(v, __shfl_xor(v, off, 64));
            if (tid == 0) sscal[0] = v;
        }
        __syncthreads();
        const float mx = sscal[0];
        if (tid < 64) sp[tid] = __expf(smv[tid] - mx);
        __syncthreads();
        if (tid < 64) {
            float s = sp[tid];
#pragma unroll
            for (int off = 32; off > 0; off >>= 1)
                s += __shfl_xor(s, off, 64);
            if (tid == 0) sscal[1] = s;
        }

        // ---- weighted E2 pooling (f32) ----
        float a0 = 0.f, a1 = 0.f;
#pragma unroll
        for (int it = 0; it < 4; ++it) {
            const int oo = it * 16 + h;
            const float wgt = sp[oo];
            a0 = fmaf(wgt, E2s[oo * 64 + j], a0);
            a1 = fmaf(wgt, E2s[oo * 64 + 32 + j], a1);
        }
        __syncthreads();
        sred[h * 64 + j]      = a0;
        sred[h * 64 + j + 32] = a1;
        __syncthreads();
        if (tid < 64) {
            float rr = 0.f;
#pragma unroll
            for (int hh = 0; hh < 16; ++hh) rr += sred[hh * 64 + tid];
            float* dst = pool + (size_t)chunk * 68;
            dst[tid] = rr;
            if (tid == 0) { dst[64] = sscal[0]; dst[65] = sscal[1]; }
        }
        __syncthreads();                      // scratch reads done before next PACK
    }
}

// ---------------------------------------------------------------------------
// K6: combine 32 chunk-partials per b with online-softmax rescale + head bias.
// ---------------------------------------------------------------------------
__global__ void k6_final(const float* __restrict__ pool, const float* __restrict__ f2b,
                         float* __restrict__ out) {
    const int b = blockIdx.x;
    const int k = threadIdx.x;   // 64 threads
    float M = -1e30f;
#pragma unroll
    for (int c = 0; c < NCHUNK; ++c)
        M = fmaxf(M, pool[(size_t)(b * NCHUNK + c) * 68 + 64]);
    float tot = 0.f, num = 0.f;
#pragma unroll
    for (int c = 0; c < NCHUNK; ++c) {
        const float* pc = pool + (size_t)(b * NCHUNK + c) * 68;
        const float sc = __expf(pc[64] - M);
        tot = fmaf(sc, pc[65], tot);
        num = fmaf(sc, pc[k], num);
    }
    out[b * KK + k] = (num / tot) * (1.f / 2048.f) + f2b[k];
}

extern "C" void kernel_launch(void* const* d_in, const int* in_sizes, int n_in,
                              void* d_out, int out_size, void* d_ws, size_t ws_size,
                              hipStream_t stream) {
    const int*   x   = (const int*)d_in[0];
    const float* V   = (const float*)d_in[1];
    const float* C   = (const float*)d_in[2];
    const float* f1w = (const float*)d_in[3];
    const float* f1b = (const float*)d_in[4];
    const float* f2w = (const float*)d_in[5];
    const float* f2b = (const float*)d_in[6];
    float* out = (float*)d_out;

    float* ws = (float*)d_ws;
    ushort* Bu = (ushort*)ws;                 // 65536 ushort = 128 KB
    float* pool = ws + 32768;                 // 1024 * 68 floats

    k1_prep <<<128, 256, 0, stream>>>(C, f2w, Bu);
    k2_fused<<<(BB * NCHUNK) / CPB, 512, 0, stream>>>(x, V, (const uint4*)Bu, f1w, f1b, pool);
    k6_final<<<BB, 64, 0, stream>>>(pool, f2b, out);
}

// Round 9
// 227.951 us; speedup vs baseline: 1.0436x; 1.0436x over previous
//
#include <hip/hip_runtime.h>
#include <hip/hip_bf16.h>

#define PP     512
#define KK     64
#define BB     32
#define LLEN   2048
#define TPOS   64           // output positions per chunk
#define SROWS  74           // 64 positions + 2*5 conv halo
#define NCHUNK (LLEN / TPOS)   // 32 chunks per batch
#define CPB    2            // chunks per block (half-payload prefetch pipeline)

typedef __attribute__((ext_vector_type(8)))  short short8;
typedef __attribute__((ext_vector_type(16))) float float16;

__device__ inline unsigned int pack_bf2(float lo, float hi) {
    __hip_bfloat162 h = __float22bfloat162_rn(make_float2(lo, hi));
    unsigned int u;
    __builtin_memcpy(&u, &h, 4);
    return u;   // low 16 = lo, high 16 = hi
}
__device__ inline float bf_lo(unsigned int v) { return __uint_as_float(v << 16); }
__device__ inline float bf_hi(unsigned int v) { return __uint_as_float(v & 0xffff0000u); }

// ---------------------------------------------------------------------------
// K1: unified B-operand fragments, 128 cols: n<64 -> l_hat[n], n>=64 -> f2w[n-64].
// Bu4[f*128 + n] = 8 bf16 of src[n][8f..8f+7] (f = 0..63).  (unchanged)
// ---------------------------------------------------------------------------
__global__ void k1_prep(const float* __restrict__ C, const float* __restrict__ f2w,
                        ushort* __restrict__ Bu) {
    const int n = blockIdx.x;            // 0..127
    const float* src = (n < 64) ? (C + n * PP) : (f2w + (n - 64) * PP);
    const int t = threadIdx.x;
    float v0 = src[t];
    float v1 = src[t + 256];
    __shared__ float red[256];
    red[t] = v0 * v0 + v1 * v1;
    __syncthreads();
    for (int s = 128; s > 0; s >>= 1) {
        if (t < s) red[t] += red[t + s];
        __syncthreads();
    }
    const float inv = (n < 64) ? rsqrtf(red[0]) : 1.f;
    Bu[(((t >> 3)       * 128 + n) << 3) + (t & 7)] = (ushort)(pack_bf2(v0 * inv, 0.f) & 0xffffu);
    Bu[((((t + 256) >> 3)) * 128 + n) * 8 + (t & 7)] = (ushort)(pack_bf2(v1 * inv, 0.f) & 0xffffu);
}

// ---------------------------------------------------------------------------
// K2 fused: r5 config (TPOS=64, 512 thr, 76KB LDS, 2 blocks/CU, cap 128) +
// HALF-payload prefetch pipeline (CPB=2): prefetch only pa[8] (32 VGPR,
// dims [0,256)) of the next chunk across MFMA+epilogue -- fits the reg
// budget at every program point (r8 lesson: full 96-reg payload spills).
// Second half (pb) + halo (ph) issue at next PACK. Wave-redundant softmax
// (shfl trees, sp via __shfl) removes 3 barriers + sscal/sp round-trips.
// Per-thread token loads drop the stok barrier. Math identical to r8 (passed).
// Output: pool[chunk][0..63]=partial, [64]=chunk max, [65]=chunk expsum.
// ---------------------------------------------------------------------------
__launch_bounds__(512, 4)   // 4 waves/EU -> 2 blocks/CU; VGPR cap 128
__global__ void k2_fused(const int* __restrict__ x, const float* __restrict__ V,
                         const uint4* __restrict__ Bu4,
                         const float* __restrict__ f1w, const float* __restrict__ f1b,
                         float* __restrict__ pool) {
    __shared__ uint4 sA[SROWS * 64];     // 75776 B; epilogue scratch aliases it
    __shared__ float rnorm[SROWS];
    __shared__ float smv[TPOS];

    const int tid  = threadIdx.x;
    const int lane = tid & 63;
    const int wv   = tid >> 6;           // 0..7
    const int l31  = lane & 31;
    const int chunk0 = blockIdx.x * CPB; // 2 consecutive chunks (same batch)

    // staging geometry: main rows 0..63 by all 512 (8 thr/row, 16 float4);
    // halo rows 64..73 by tid 352..511 (16 thr/row, 8 float4)
    const int o   = tid & 7;
    const int r   = tid >> 3;
    const int ht  = tid - 352;
    const int h16 = ht & 15;
    const int rh  = 64 + (ht >> 4);

    float4 pa[8], pb[8], ph[8];
    float  nrmM = 0.f;

    // MFMA tile assignment (5 waves): cos staged-rows {0-31,32-63,42-73},
    // E2 staged-rows {5-36,37-68}
    const int rowBase = (wv == 0) ? 0 : (wv == 1) ? 32 : (wv == 2) ? 42
                      : (wv == 3) ? 5 : 37;
    const int cc = lane >> 5;

    // epilogue constants
    float w[11];
#pragma unroll
    for (int t = 0; t < 11; ++t) w[t] = f1w[t];
    const int j = l31;
    const int h = tid >> 5;                              // 0..15
    const float bias0 = f1b[j], bias1 = f1b[j + 32];

    auto ISSUE_A = [&](int chunk) {      // dims [0,256) of main rows: 32 VGPR
        const int bb = chunk >> 5;
        const int l0c = (chunk & 31) * TPOS;
        const int gl  = min(max(l0c - 5 + r, 0), LLEN - 1);
        const int tok = x[bb * LLEN + gl];
        const float4* f4 = (const float4*)(V + (size_t)tok * PP);
#pragma unroll
        for (int g = 0; g < 8; ++g) pa[g] = f4[o + g * 8];
    };
    auto ISSUE_BH = [&](int chunk) {     // dims [256,512) + halo rows
        const int bb = chunk >> 5;
        const int l0c = (chunk & 31) * TPOS;
        const int gl  = min(max(l0c - 5 + r, 0), LLEN - 1);
        const int tok = x[bb * LLEN + gl];
        const float4* f4 = (const float4*)(V + (size_t)tok * PP);
#pragma unroll
        for (int g = 0; g < 8; ++g) pb[g] = f4[o + (g + 8) * 8];
        if (ht >= 0) {
            const int glh  = min(max(l0c - 5 + rh, 0), LLEN - 1);
            const int tokh = x[bb * LLEN + glh];
            const float4* f4h = (const float4*)(V + (size_t)tokh * PP);
#pragma unroll
            for (int g = 0; g < 8; ++g) ph[g] = f4h[h16 + g * 16];
        }
    };
    auto PACK_A = [&]() {
        const int swzr = r & 7;
        nrmM = 0.f;
#pragma unroll
        for (int g = 0; g < 8; ++g) {
            const float4 a = pa[g];
            nrmM = fmaf(a.x, a.x, fmaf(a.y, a.y, fmaf(a.z, a.z, fmaf(a.w, a.w, nrmM))));
            uint2 w2; w2.x = pack_bf2(a.x, a.y); w2.y = pack_bf2(a.z, a.w);
            const int f = g * 4 + (o >> 1);
            ((uint2*)&sA[r * 64 + (f ^ swzr)])[o & 1] = w2;
        }
    };
    auto PACK_BH = [&]() {
        const int swzr = r & 7;
#pragma unroll
        for (int g = 0; g < 8; ++g) {
            const float4 a = pb[g];
            nrmM = fmaf(a.x, a.x, fmaf(a.y, a.y, fmaf(a.z, a.z, fmaf(a.w, a.w, nrmM))));
            uint2 w2; w2.x = pack_bf2(a.x, a.y); w2.y = pack_bf2(a.z, a.w);
            const int f = (g + 8) * 4 + (o >> 1);
            ((uint2*)&sA[r * 64 + (f ^ swzr)])[o & 1] = w2;
        }
        float nm = nrmM;
        nm += __shfl_xor(nm, 1, 64);
        nm += __shfl_xor(nm, 2, 64);
        nm += __shfl_xor(nm, 4, 64);
        if (o == 0) rnorm[r] = rsqrtf(nm);
        if (ht >= 0) {
            const int swzh = rh & 7;
            float nh2 = 0.f;
#pragma unroll
            for (int g = 0; g < 8; ++g) {
                const float4 a = ph[g];
                nh2 = fmaf(a.x, a.x, fmaf(a.y, a.y, fmaf(a.z, a.z, fmaf(a.w, a.w, nh2))));
                uint2 w2; w2.x = pack_bf2(a.x, a.y); w2.y = pack_bf2(a.z, a.w);
                const int f = g * 8 + (h16 >> 1);
                ((uint2*)&sA[rh * 64 + (f ^ swzh)])[h16 & 1] = w2;
            }
            nh2 += __shfl_xor(nh2, 1, 64);
            nh2 += __shfl_xor(nh2, 2, 64);
            nh2 += __shfl_xor(nh2, 4, 64);
            nh2 += __shfl_xor(nh2, 8, 64);
            if (h16 == 0) rnorm[rh] = rsqrtf(nh2);
        }
    };

    ISSUE_A(chunk0);                     // prologue: full first-chunk gather
    ISSUE_BH(chunk0);                    // (exposed, as in r5)

#pragma unroll
    for (int i = 0; i < CPB; ++i) {
        const int chunk = chunk0 + i;
        const int l0 = (chunk & 31) * TPOS;

        if (i > 0) ISSUE_BH(chunk);      // second half of pipelined chunk
        PACK_A();                        // (packing pa covers part of BH latency)
        PACK_BH();
        __syncthreads();                 // sA staged

        if (i + 1 < CPB) {
            ISSUE_A(chunk + 1);          // 32-VGPR prefetch flies across MFMA+epilogue
            __builtin_amdgcn_sched_barrier(0);
        }

        // ---- MFMA: 5 wave-tiles of 32 rows x 64 cols ----
        float16 c0, c1;
#pragma unroll
        for (int k = 0; k < 16; ++k) { c0[k] = 0.f; c1[k] = 0.f; }
        if (wv < 5) {
            const int nh    = (wv < 3) ? 0 : 64;   // cos cols 0-63 / E2 cols 64-127
            const int row   = rowBase + l31;
            const int abase = row * 64;
            const int aswz  = row & 7;
#pragma unroll 8
            for (int ks = 0; ks < 32; ++ks) {
                const int ff = ks * 2 + cc;
                const uint4 av = sA[abase + (ff ^ aswz)];
                const uint4 b0 = Bu4[ff * 128 + nh + l31];
                const uint4 b1 = Bu4[ff * 128 + nh + 32 + l31];
                short8 a8, t0, t1;
                __builtin_memcpy(&a8, &av, 16);
                __builtin_memcpy(&t0, &b0, 16);
                __builtin_memcpy(&t1, &b1, 16);
                c0 = __builtin_amdgcn_mfma_f32_32x32x16_bf16(a8, t0, c0, 0, 0, 0);
                c1 = __builtin_amdgcn_mfma_f32_32x32x16_bf16(a8, t1, c1, 0, 0, 0);
            }
        }
        __syncthreads();                 // MFMA reads of sA done -> alias ok

        // ---- epilogue: scratch aliases dead sA ----
        unsigned int* G32 = (unsigned int*)sA;             // [74][32] pairs: 9472 B
        float*        E2s = (float*)((char*)sA + 10240);   // [64][64] f32
        float*        sred = (float*)((char*)sA + 28672);  // [16][64] f32
        if (wv < 3) {                                       // cos waves
#pragma unroll
            for (int reg = 0; reg < 16; ++reg) {
                const int rr  = (reg & 3) + 8 * (reg >> 2) + 4 * cc;
                const int row = rowBase + rr;
                if (wv == 2 && row < 64) continue;          // wv1 owns overlap rows
                const int gl = l0 - 5 + row;
                unsigned int vpk = 0u;
                if (gl >= 0 && gl < LLEN) {
                    const float rn = rnorm[row];
                    vpk = pack_bf2(c0[reg] * rn, c1[reg] * rn);
                }
                G32[row * 32 + l31] = vpk;
            }
        } else if (wv < 5) {                                // E2 waves
#pragma unroll
            for (int reg = 0; reg < 16; ++reg) {
                const int rr = (reg & 3) + 8 * (reg >> 2) + 4 * cc;
                const int oo = rowBase - 5 + rr;            // 0..63
                E2s[oo * 64 + l31]      = c0[reg];
                E2s[oo * 64 + 32 + l31] = c1[reg];
            }
        }
        __syncthreads();

        // ---- conv(11) + relu + max over k ----
#pragma unroll
        for (int it = 0; it < 4; ++it) {
            const int oo = it * 16 + h;                     // output row 0..63
            float u0 = 0.f, u1 = 0.f;
#pragma unroll
            for (int tap = 0; tap < 11; ++tap) {
                const unsigned int v = G32[(oo + tap) * 32 + j];
                u0 = fmaf(bf_lo(v), w[tap], u0);
                u1 = fmaf(bf_hi(v), w[tap], u1);
            }
            float m = fmaxf(fmaxf(u0 + bias0, 0.f), fmaxf(u1 + bias1, 0.f));
#pragma unroll
            for (int off = 16; off > 0; off >>= 1)
                m = fmaxf(m, __shfl_xor(m, off, 64));       // reduce 32-lane half
            if (j == 0) smv[oo] = m;
        }
        __syncthreads();

        // ---- wave-redundant softmax: every wave computes identical
        //      max/exp/sum of smv[0..63] via shfl trees (0 barriers) ----
        float v = smv[lane];
        float mxv = v;
#pragma unroll
        for (int off = 32; off > 0; off >>= 1)
            mxv = fmaxf(mxv, __shfl_xor(mxv, off, 64));
        const float spv = __expf(v - mxv);
        float sumv = spv;
#pragma unroll
        for (int off = 32; off > 0; off >>= 1)
            sumv += __shfl_xor(sumv, off, 64);

        // ---- weighted E2 pooling (f32); sp fetched lane->lane via shfl ----
        float a0 = 0.f, a1 = 0.f;
#pragma unroll
        for (int it = 0; it < 4; ++it) {
            const int oo = it * 16 + h;
            const float wgt = __shfl(spv, oo, 64);
            a0 = fmaf(wgt, E2s[oo * 64 + j], a0);
            a1 = fmaf(wgt, E2s[oo * 64 + 32 + j], a1);
        }
        sred[h * 64 + j]      = a0;
        sred[h * 64 + j + 32] = a1;
        __syncthreads();
        if (tid < 64) {
            float rr = 0.f;
#pragma unroll
            for (int hh = 0; hh < 16; ++hh) rr += sred[hh * 64 + tid];
            float* dst = pool + (size_t)chunk * 68;
            dst[tid] = rr;
            if (tid == 0) { dst[64] = mxv; dst[65] = sumv; }
        }
        __syncthreads();                 // sred reads done before next PACK
    }
}

// ---------------------------------------------------------------------------
// K6: combine 32 chunk-partials per b with online-softmax rescale + head bias.
// ---------------------------------------------------------------------------
__global__ void k6_final(const float* __restrict__ pool, const float* __restrict__ f2b,
                         float* __restrict__ out) {
    const int b = blockIdx.x;
    const int k = threadIdx.x;   // 64 threads
    float M = -1e30f;
#pragma unroll
    for (int c = 0; c < NCHUNK; ++c)
        M = fmaxf(M, pool[(size_t)(b * NCHUNK + c) * 68 + 64]);
    float tot = 0.f, num = 0.f;
#pragma unroll
    for (int c = 0; c < NCHUNK; ++c) {
        const float* pc = pool + (size_t)(b * NCHUNK + c) * 68;
        const float sc = __expf(pc[64] - M);
        tot = fmaf(sc, pc[65], tot);
        num = fmaf(sc, pc[k], num);
    }
    out[b * KK + k] = (num / tot) * (1.f / 2048.f) + f2b[k];
}

extern "C" void kernel_launch(void* const* d_in, const int* in_sizes, int n_in,
                              void* d_out, int out_size, void* d_ws, size_t ws_size,
                              hipStream_t stream) {
    const int*   x   = (const int*)d_in[0];
    const float* V   = (const float*)d_in[1];
    const float* C   = (const float*)d_in[2];
    const float* f1w = (const float*)d_in[3];
    const float* f1b = (const float*)d_in[4];
    const float* f2w = (const float*)d_in[5];
    const float* f2b = (const float*)d_in[6];
    float* out = (float*)d_out;

    float* ws = (float*)d_ws;
    ushort* Bu = (ushort*)ws;                 // 65536 ushort = 128 KB
    float* pool = ws + 32768;                 // 1024 * 68 floats

    k1_prep <<<128, 256, 0, stream>>>(C, f2w, Bu);
    k2_fused<<<(BB * NCHUNK) / CPB, 512, 0, stream>>>(x, V, (const uint4*)Bu, f1w, f1b, pool);
    k6_final<<<BB, 64, 0, stream>>>(pool, f2b, out);
}

// Round 10
// 206.427 us; speedup vs baseline: 1.1524x; 1.1043x over previous
//
#include <hip/hip_runtime.h>
#include <hip/hip_bf16.h>

#define VOCAB  50257
#define PP     512
#define KK     64
#define BB     32
#define LLEN   2048
#define TPOS   64           // output positions per chunk
#define SROWS  74           // 64 positions + 2*5 conv halo
#define NCHUNK (LLEN / TPOS)   // 32 chunks per batch

typedef __attribute__((ext_vector_type(8)))  short short8;
typedef __attribute__((ext_vector_type(16))) float float16;

typedef __attribute__((address_space(1))) const void g_as_void;
typedef __attribute__((address_space(3))) void lds_as_void;

__device__ inline unsigned int pack_bf2(float lo, float hi) {
    __hip_bfloat162 h = __float22bfloat162_rn(make_float2(lo, hi));
    unsigned int u;
    __builtin_memcpy(&u, &h, 4);
    return u;   // low 16 = lo, high 16 = hi
}
__device__ inline float bf_lo(unsigned int v) { return __uint_as_float(v << 16); }
__device__ inline float bf_hi(unsigned int v) { return __uint_as_float(v & 0xffff0000u); }

// ---------------------------------------------------------------------------
// K1: unified B-operand fragments, 128 cols: n<64 -> l_hat[n], n>=64 -> f2w[n-64].
// Bu4[f*128 + n] = 8 bf16 of src[n][8f..8f+7] (f = 0..63).  (unchanged)
// ---------------------------------------------------------------------------
__global__ void k1_prep(const float* __restrict__ C, const float* __restrict__ f2w,
                        ushort* __restrict__ Bu) {
    const int n = blockIdx.x;            // 0..127
    const float* src = (n < 64) ? (C + n * PP) : (f2w + (n - 64) * PP);
    const int t = threadIdx.x;
    float v0 = src[t];
    float v1 = src[t + 256];
    __shared__ float red[256];
    red[t] = v0 * v0 + v1 * v1;
    __syncthreads();
    for (int s = 128; s > 0; s >>= 1) {
        if (t < s) red[t] += red[t + s];
        __syncthreads();
    }
    const float inv = (n < 64) ? rsqrtf(red[0]) : 1.f;
    Bu[(((t >> 3)       * 128 + n) << 3) + (t & 7)] = (ushort)(pack_bf2(v0 * inv, 0.f) & 0xffffu);
    Bu[((((t + 256) >> 3)) * 128 + n) * 8 + (t & 7)] = (ushort)(pack_bf2(v1 * inv, 0.f) & 0xffffu);
}

// ---------------------------------------------------------------------------
// K1V: stream V once (sequential, ~6.3 TB/s) -> pre-NORMALIZED bf16 table Vb
// (51.5 MB, lands in L3, stays hot for k2 within this iteration) + per-token
// norm table vnorm (for E2 scale-back). One row per 64-lane wave.
// ---------------------------------------------------------------------------
__global__ void k1v_prep(const float* __restrict__ V, ushort* __restrict__ Vb,
                         float* __restrict__ vnorm) {
    const int wid  = (blockIdx.x * blockDim.x + threadIdx.x) >> 6;  // row
    const int lane = threadIdx.x & 63;
    if (wid >= VOCAB) return;
    const float4* src = (const float4*)(V + (size_t)wid * PP) + lane * 2;
    const float4 a = src[0], b = src[1];
    float ss = a.x * a.x + a.y * a.y + a.z * a.z + a.w * a.w
             + b.x * b.x + b.y * b.y + b.z * b.z + b.w * b.w;
#pragma unroll
    for (int off = 32; off > 0; off >>= 1) ss += __shfl_xor(ss, off, 64);
    const float inv = rsqrtf(ss);
    uint4 pk;
    pk.x = pack_bf2(a.x * inv, a.y * inv);
    pk.y = pack_bf2(a.z * inv, a.w * inv);
    pk.z = pack_bf2(b.x * inv, b.y * inv);
    pk.w = pack_bf2(b.z * inv, b.w * inv);
    ((uint4*)(Vb + (size_t)wid * PP))[lane] = pk;
    if (lane == 0) vnorm[wid] = ss * inv;    // = sqrt(ss): E2 scale-back factor
}

// ---------------------------------------------------------------------------
// K2 fused: staging via ASYNC global_load_lds from the bf16 L3-hot table --
// 74 x dwordx4 row-loads per block (one row per wave-instruction, 74 KB in
// flight), ZERO payload VGPRs, zero pack VALU -> no spill possible (r3/r8/r9
// lesson). Swizzle via pre-swizzled per-lane GLOBAL address (slot lane holds
// frag lane^swzr). Cos rows pre-normalized (no rn multiply); E2 scaled back
// by snorm at scatter. Epilogue (conv/softmax/pool) = r9's verified math.
// Output: pool[chunk][0..63]=partial, [64]=chunk max, [65]=chunk expsum.
// ---------------------------------------------------------------------------
__launch_bounds__(512, 4)   // 4 waves/EU -> 2 blocks/CU (LDS 76 KB)
__global__ void k2_fused(const int* __restrict__ x, const ushort* __restrict__ Vb,
                         const float* __restrict__ vnorm, const uint4* __restrict__ Bu4,
                         const float* __restrict__ f1w, const float* __restrict__ f1b,
                         float* __restrict__ pool) {
    __shared__ uint4 sA[SROWS * 64];     // 75776 B; epilogue scratch aliases it
    __shared__ int   stok[SROWS];
    __shared__ float snorm[SROWS];
    __shared__ float smv[TPOS];

    const int tid  = threadIdx.x;
    const int lane = tid & 63;
    const int wv   = tid >> 6;           // 0..7
    const int l31  = lane & 31;
    const int b    = blockIdx.x >> 5;
    const int l0   = (blockIdx.x & 31) * TPOS;

    if (tid < SROWS) {
        int gl = min(max(l0 - 5 + tid, 0), LLEN - 1);   // clamp; zeroed at G-write
        const int t = x[b * LLEN + gl];
        stok[tid]  = t;
        snorm[tid] = vnorm[t];
    }
    __syncthreads();

    // ---- async staging: wave w loads rows w, w+8, ... (1 KB row per inst) ----
    for (int row = wv; row < SROWS; row += 8) {
        const int tok  = stok[row];
        const int swzr = row & 7;
        const ushort* src = Vb + (size_t)tok * PP + ((lane ^ swzr) << 3);
        __builtin_amdgcn_global_load_lds((g_as_void*)src,
                                         (lds_as_void*)&sA[row * 64], 16, 0, 0);
    }
    __syncthreads();   // compiler drains vmcnt before barrier -> sA staged

    // ---- MFMA: 5 wave-tiles of 32 rows x 64 cols, one per wave ----
    float16 c0, c1;
#pragma unroll
    for (int k = 0; k < 16; ++k) { c0[k] = 0.f; c1[k] = 0.f; }

    const int rowBase = (wv == 0) ? 0 : (wv == 1) ? 32 : (wv == 2) ? 42
                      : (wv == 3) ? 5 : 37;
    const int cc = lane >> 5;
    if (wv < 5) {
        const int nh    = (wv < 3) ? 0 : 64;   // cos cols 0-63 / E2 cols 64-127
        const int row   = rowBase + l31;
        const int abase = row * 64;
        const int aswz  = row & 7;
#pragma unroll 8
        for (int ks = 0; ks < 32; ++ks) {
            const int ff = ks * 2 + cc;
            const uint4 av = sA[abase + (ff ^ aswz)];
            const uint4 b0 = Bu4[ff * 128 + nh + l31];
            const uint4 b1 = Bu4[ff * 128 + nh + 32 + l31];
            short8 a8, t0, t1;
            __builtin_memcpy(&a8, &av, 16);
            __builtin_memcpy(&t0, &b0, 16);
            __builtin_memcpy(&t1, &b1, 16);
            c0 = __builtin_amdgcn_mfma_f32_32x32x16_bf16(a8, t0, c0, 0, 0, 0);
            c1 = __builtin_amdgcn_mfma_f32_32x32x16_bf16(a8, t1, c1, 0, 0, 0);
        }
    }
    __syncthreads();   // all A-tile reads done -> safe to alias sA

    // ---- scatter results into aliased LDS ----
    unsigned int* G32 = (unsigned int*)sA;             // [74][32] pairs: 9472 B
    float*        E2s = (float*)((char*)sA + 10240);   // [64][64] f32
    float*        sred = (float*)((char*)sA + 28672);  // [16][64] f32
    if (wv < 3) {                                       // cos waves (already normalized)
#pragma unroll
        for (int reg = 0; reg < 16; ++reg) {
            const int rr  = (reg & 3) + 8 * (reg >> 2) + 4 * cc;
            const int row = rowBase + rr;
            if (wv == 2 && row < 64) continue;          // wv1 owns overlap rows
            const int gl = l0 - 5 + row;
            unsigned int vpk = 0u;
            if (gl >= 0 && gl < LLEN)
                vpk = pack_bf2(c0[reg], c1[reg]);
            G32[row * 32 + l31] = vpk;
        }
    } else if (wv < 5) {                                // E2 waves: scale back by norm
#pragma unroll
        for (int reg = 0; reg < 16; ++reg) {
            const int rr = (reg & 3) + 8 * (reg >> 2) + 4 * cc;
            const int row = rowBase + rr;               // staged row 5..68
            const int oo  = row - 5;                    // output pos 0..63
            const float sn = snorm[row];
            E2s[oo * 64 + l31]      = c0[reg] * sn;
            E2s[oo * 64 + 32 + l31] = c1[reg] * sn;
        }
    }
    __syncthreads();

    // ---- conv(11) + relu + max over k (512 threads: 16 rows/iter) ----
    float w[11];
#pragma unroll
    for (int t = 0; t < 11; ++t) w[t] = f1w[t];
    const int j = l31;
    const int h = tid >> 5;                              // 0..15
    const float bias0 = f1b[j], bias1 = f1b[j + 32];
#pragma unroll
    for (int it = 0; it < 4; ++it) {
        const int oo = it * 16 + h;                      // output row 0..63
        float u0 = 0.f, u1 = 0.f;
#pragma unroll
        for (int tap = 0; tap < 11; ++tap) {
            const unsigned int v = G32[(oo + tap) * 32 + j];
            u0 = fmaf(bf_lo(v), w[tap], u0);
            u1 = fmaf(bf_hi(v), w[tap], u1);
        }
        float m = fmaxf(fmaxf(u0 + bias0, 0.f), fmaxf(u1 + bias1, 0.f));
#pragma unroll
        for (int off = 16; off > 0; off >>= 1)
            m = fmaxf(m, __shfl_xor(m, off, 64));        // reduce 32-lane half
        if (j == 0) smv[oo] = m;
    }
    __syncthreads();

    // ---- wave-redundant softmax: every wave computes identical
    //      max/exp/sum of smv[0..63] via shfl trees (0 barriers) ----
    const float v = smv[lane];
    float mxv = v;
#pragma unroll
    for (int off = 32; off > 0; off >>= 1)
        mxv = fmaxf(mxv, __shfl_xor(mxv, off, 64));
    const float spv = __expf(v - mxv);
    float sumv = spv;
#pragma unroll
    for (int off = 32; off > 0; off >>= 1)
        sumv += __shfl_xor(sumv, off, 64);

    // ---- weighted E2 pooling (f32); weights fetched lane->lane via shfl ----
    float a0 = 0.f, a1 = 0.f;
#pragma unroll
    for (int it = 0; it < 4; ++it) {
        const int oo = it * 16 + h;
        const float wgt = __shfl(spv, oo, 64);
        a0 = fmaf(wgt, E2s[oo * 64 + j], a0);
        a1 = fmaf(wgt, E2s[oo * 64 + 32 + j], a1);
    }
    sred[h * 64 + j]      = a0;
    sred[h * 64 + j + 32] = a1;
    __syncthreads();
    if (tid < 64) {
        float rr = 0.f;
#pragma unroll
        for (int hh = 0; hh < 16; ++hh) rr += sred[hh * 64 + tid];
        float* dst = pool + (size_t)blockIdx.x * 68;
        dst[tid] = rr;
        if (tid == 0) { dst[64] = mxv; dst[65] = sumv; }
    }
}

// ---------------------------------------------------------------------------
// K6: combine 32 chunk-partials per b with online-softmax rescale + head bias.
// ---------------------------------------------------------------------------
__global__ void k6_final(const float* __restrict__ pool, const float* __restrict__ f2b,
                         float* __restrict__ out) {
    const int b = blockIdx.x;
    const int k = threadIdx.x;   // 64 threads
    float M = -1e30f;
#pragma unroll
    for (int c = 0; c < NCHUNK; ++c)
        M = fmaxf(M, pool[(size_t)(b * NCHUNK + c) * 68 + 64]);
    float tot = 0.f, num = 0.f;
#pragma unroll
    for (int c = 0; c < NCHUNK; ++c) {
        const float* pc = pool + (size_t)(b * NCHUNK + c) * 68;
        const float sc = __expf(pc[64] - M);
        tot = fmaf(sc, pc[65], tot);
        num = fmaf(sc, pc[k], num);
    }
    out[b * KK + k] = (num / tot) * (1.f / 2048.f) + f2b[k];
}

extern "C" void kernel_launch(void* const* d_in, const int* in_sizes, int n_in,
                              void* d_out, int out_size, void* d_ws, size_t ws_size,
                              hipStream_t stream) {
    const int*   x   = (const int*)d_in[0];
    const float* V   = (const float*)d_in[1];
    const float* C   = (const float*)d_in[2];
    const float* f1w = (const float*)d_in[3];
    const float* f1b = (const float*)d_in[4];
    const float* f2w = (const float*)d_in[5];
    const float* f2b = (const float*)d_in[6];
    float* out = (float*)d_out;

    float* ws = (float*)d_ws;
    ushort* Bu   = (ushort*)ws;               // 65536 ushort = 128 KB
    float*  pool = ws + 32768;                // 1024 * 68 floats = 278 KB
    float*  vnorm = ws + 32768 + 69632;       // 50257 floats (pad to 50432)
    ushort* Vb   = (ushort*)(ws + 32768 + 69632 + 50432);   // 50257*512 bf16 = 51.5 MB

    k1_prep <<<128, 256, 0, stream>>>(C, f2w, Bu);
    k1v_prep<<<(VOCAB + 3) / 4, 256, 0, stream>>>(V, Vb, vnorm);
    k2_fused<<<BB * NCHUNK, 512, 0, stream>>>(x, Vb, vnorm, (const uint4*)Bu,
                                              f1w, f1b, pool);
    k6_final<<<BB, 64, 0, stream>>>(pool, f2b, out);
}

// Round 11
// 184.775 us; speedup vs baseline: 1.2875x; 1.1172x over previous
//
#include <hip/hip_runtime.h>
#include <hip/hip_bf16.h>

#define PP     512
#define KK     64
#define BB     32
#define LLEN   2048
#define TPOS   64           // output positions per chunk
#define SROWS  74           // 64 positions + 2*5 conv halo
#define NCHUNK (LLEN / TPOS)   // 32 chunks per batch

typedef __attribute__((ext_vector_type(8)))  short short8;
typedef __attribute__((ext_vector_type(16))) float float16;

__device__ inline unsigned int pack_bf2(float lo, float hi) {
    __hip_bfloat162 h = __float22bfloat162_rn(make_float2(lo, hi));
    unsigned int u;
    __builtin_memcpy(&u, &h, 4);
    return u;   // low 16 = lo, high 16 = hi
}
__device__ inline float bf_lo(unsigned int v) { return __uint_as_float(v << 16); }
__device__ inline float bf_hi(unsigned int v) { return __uint_as_float(v & 0xffff0000u); }

// ---------------------------------------------------------------------------
// K1: unified B-operand fragments, 128 cols: n<64 -> l_hat[n], n>=64 -> f2w[n-64].
// Bu4[f*128 + n] = 8 bf16 of src[n][8f..8f+7] (f = 0..63).  (unchanged)
// ---------------------------------------------------------------------------
__global__ void k1_prep(const float* __restrict__ C, const float* __restrict__ f2w,
                        ushort* __restrict__ Bu) {
    const int n = blockIdx.x;            // 0..127
    const float* src = (n < 64) ? (C + n * PP) : (f2w + (n - 64) * PP);
    const int t = threadIdx.x;
    float v0 = src[t];
    float v1 = src[t + 256];
    __shared__ float red[256];
    red[t] = v0 * v0 + v1 * v1;
    __syncthreads();
    for (int s = 128; s > 0; s >>= 1) {
        if (t < s) red[t] += red[t + s];
        __syncthreads();
    }
    const float inv = (n < 64) ? rsqrtf(red[0]) : 1.f;
    Bu[(((t >> 3)       * 128 + n) << 3) + (t & 7)] = (ushort)(pack_bf2(v0 * inv, 0.f) & 0xffffu);
    Bu[((((t + 256) >> 3)) * 128 + n) * 8 + (t & 7)] = (ushort)(pack_bf2(v1 * inv, 0.f) & 0xffffu);
}

// ---------------------------------------------------------------------------
// K2 fused = r5's proven base (TPOS=64, 512 thr, 76KB LDS, 2 blocks/CU,
// full-K single-pass f32 staging, no prefetch -- r3/r8/r9 all spilled) +
// serial-overhead cuts verified in r9: per-thread token loads (drops the
// stok array + its barrier + dependent-load chain) and wave-redundant shfl
// softmax (drops 3 barriers + sscal/sp LDS round-trips). 5 barriers total
// (was 9). r10 lesson: gather is latency/duty-cycle-bound, not bytes-bound
// (bf16 L3-hot table saved only ~4us at +25us prep) -- so no Vb table.
// Output: pool[chunk][0..63]=partial, [64]=chunk max, [65]=chunk expsum.
// ---------------------------------------------------------------------------
__launch_bounds__(512, 4)   // 4 waves/EU -> 2 blocks/CU; VGPR cap 128 (no spill)
__global__ void k2_fused(const int* __restrict__ x, const float* __restrict__ V,
                         const uint4* __restrict__ Bu4,
                         const float* __restrict__ f1w, const float* __restrict__ f1b,
                         float* __restrict__ pool) {
    __shared__ uint4 sA[SROWS * 64];     // 75776 B; epilogue scratch aliases it
    __shared__ float rnorm[SROWS];
    __shared__ float smv[TPOS];

    const int tid  = threadIdx.x;
    const int lane = tid & 63;
    const int wv   = tid >> 6;           // 0..7
    const int l31  = lane & 31;
    const int b    = blockIdx.x >> 5;
    const int l0   = (blockIdx.x & 31) * TPOS;

    // ---- staging pass 1: rows 0..63, 8 thr/row, per-thread token load ----
    {
        const int o = tid & 7;            // octet position within row
        const int r = tid >> 3;           // 0..63
        const int gl  = min(max(l0 - 5 + r, 0), LLEN - 1);
        const int tok = x[b * LLEN + gl];           // 8x redundant, L1/L2-hit
        const float* src = V + (size_t)tok * PP + o * 4;
        const int swzr = r & 7;
        float nrm = 0.f;
        float4 pa[8];
#pragma unroll
        for (int g = 0; g < 8; ++g) pa[g] = ((const float4*)src)[g * 8];
        float4 pb[8];
#pragma unroll
        for (int g = 0; g < 8; ++g) pb[g] = ((const float4*)src)[(g + 8) * 8];
#pragma unroll
        for (int g = 0; g < 8; ++g) {
            const float4 a = pa[g];
            nrm = fmaf(a.x, a.x, fmaf(a.y, a.y, fmaf(a.z, a.z, fmaf(a.w, a.w, nrm))));
            uint2 w2; w2.x = pack_bf2(a.x, a.y); w2.y = pack_bf2(a.z, a.w);
            const int f = g * 4 + (o >> 1);          // float off = o*4+g*32 -> frag f
            ((uint2*)&sA[r * 64 + (f ^ swzr)])[o & 1] = w2;
        }
#pragma unroll
        for (int g = 0; g < 8; ++g) {
            const float4 a = pb[g];
            nrm = fmaf(a.x, a.x, fmaf(a.y, a.y, fmaf(a.z, a.z, fmaf(a.w, a.w, nrm))));
            uint2 w2; w2.x = pack_bf2(a.x, a.y); w2.y = pack_bf2(a.z, a.w);
            const int f = (g + 8) * 4 + (o >> 1);
            ((uint2*)&sA[r * 64 + (f ^ swzr)])[o & 1] = w2;
        }
        nrm += __shfl_xor(nrm, 1, 64);
        nrm += __shfl_xor(nrm, 2, 64);
        nrm += __shfl_xor(nrm, 4, 64);
        if (o == 0) rnorm[r] = rsqrtf(nrm);
    }
    // ---- staging pass 2: halo rows 64..73, 16 thr/row, per-thread token ----
    if (tid < 160) {
        const int h16 = tid & 15;
        const int r   = 64 + (tid >> 4);  // 64..73
        const int gl  = min(max(l0 - 5 + r, 0), LLEN - 1);
        const int tok = x[b * LLEN + gl];
        const float* src = V + (size_t)tok * PP + h16 * 4;
        const int swzr = r & 7;
        float nrm = 0.f;
        float4 ph[8];
#pragma unroll
        for (int g = 0; g < 8; ++g) ph[g] = ((const float4*)src)[g * 16];
#pragma unroll
        for (int g = 0; g < 8; ++g) {
            const float4 a = ph[g];
            nrm = fmaf(a.x, a.x, fmaf(a.y, a.y, fmaf(a.z, a.z, fmaf(a.w, a.w, nrm))));
            uint2 w2; w2.x = pack_bf2(a.x, a.y); w2.y = pack_bf2(a.z, a.w);
            const int f = g * 8 + (h16 >> 1);        // float off = h16*4+g*64
            ((uint2*)&sA[r * 64 + (f ^ swzr)])[h16 & 1] = w2;
        }
        nrm += __shfl_xor(nrm, 1, 64);
        nrm += __shfl_xor(nrm, 2, 64);
        nrm += __shfl_xor(nrm, 4, 64);
        nrm += __shfl_xor(nrm, 8, 64);
        if (h16 == 0) rnorm[r] = rsqrtf(nrm);
    }
    __syncthreads();                                 // [B1] sA + rnorm staged

    // ---- MFMA: 5 wave-tiles of 32 rows x 64 cols, one per wave ----
    float16 c0, c1;
#pragma unroll
    for (int k = 0; k < 16; ++k) { c0[k] = 0.f; c1[k] = 0.f; }

    const int rowBase = (wv == 0) ? 0 : (wv == 1) ? 32 : (wv == 2) ? 42
                      : (wv == 3) ? 5 : 37;
    const int cc = lane >> 5;
    if (wv < 5) {
        const int nh    = (wv < 3) ? 0 : 64;          // cos cols 0-63 / E2 cols 64-127
        const int row   = rowBase + l31;
        const int abase = row * 64;
        const int aswz  = row & 7;
#pragma unroll 8
        for (int ks = 0; ks < 32; ++ks) {
            const int ff = ks * 2 + cc;
            const uint4 av = sA[abase + (ff ^ aswz)];
            const uint4 b0 = Bu4[ff * 128 + nh + l31];
            const uint4 b1 = Bu4[ff * 128 + nh + 32 + l31];
            short8 a8, t0, t1;
            __builtin_memcpy(&a8, &av, 16);
            __builtin_memcpy(&t0, &b0, 16);
            __builtin_memcpy(&t1, &b1, 16);
            c0 = __builtin_amdgcn_mfma_f32_32x32x16_bf16(a8, t0, c0, 0, 0, 0);
            c1 = __builtin_amdgcn_mfma_f32_32x32x16_bf16(a8, t1, c1, 0, 0, 0);
        }
    }
    __syncthreads();                                 // [B2] sA dead -> alias ok

    // ---- scatter results into aliased LDS ----
    unsigned int* G32 = (unsigned int*)sA;             // [74][32] pairs: 9472 B
    float*        E2s = (float*)((char*)sA + 10240);   // [64][64] f32 (ends 26624)
    float*        sred = (float*)((char*)sA + 28672);  // [16][64] f32 (ends 32768)
    if (wv < 3) {                                       // cos waves
#pragma unroll
        for (int reg = 0; reg < 16; ++reg) {
            const int rr  = (reg & 3) + 8 * (reg >> 2) + 4 * cc;
            const int row = rowBase + rr;
            if (wv == 2 && row < 64) continue;          // wv1 owns overlap rows
            const int gl = l0 - 5 + row;
            unsigned int vpk = 0u;
            if (gl >= 0 && gl < LLEN) {
                const float rn = rnorm[row];
                vpk = pack_bf2(c0[reg] * rn, c1[reg] * rn);
            }
            G32[row * 32 + l31] = vpk;
        }
    } else if (wv < 5) {                                // E2 waves
#pragma unroll
        for (int reg = 0; reg < 16; ++reg) {
            const int rr = (reg & 3) + 8 * (reg >> 2) + 4 * cc;
            const int oo = rowBase - 5 + rr;            // 0..63
            E2s[oo * 64 + l31]      = c0[reg];
            E2s[oo * 64 + 32 + l31] = c1[reg];
        }
    }
    __syncthreads();                                 // [B3] G32/E2s ready

    // ---- conv(11) + relu + max over k (512 threads: 16 rows/iter) ----
    float w[11];
#pragma unroll
    for (int t = 0; t < 11; ++t) w[t] = f1w[t];
    const int j = l31;
    const int h = tid >> 5;                              // 0..15
    const float bias0 = f1b[j], bias1 = f1b[j + 32];
#pragma unroll
    for (int it = 0; it < 4; ++it) {
        const int oo = it * 16 + h;                      // output row 0..63
        float u0 = 0.f, u1 = 0.f;
#pragma unroll
        for (int tap = 0; tap < 11; ++tap) {
            const unsigned int v = G32[(oo + tap) * 32 + j];
            u0 = fmaf(bf_lo(v), w[tap], u0);
            u1 = fmaf(bf_hi(v), w[tap], u1);
        }
        float m = fmaxf(fmaxf(u0 + bias0, 0.f), fmaxf(u1 + bias1, 0.f));
#pragma unroll
        for (int off = 16; off > 0; off >>= 1)
            m = fmaxf(m, __shfl_xor(m, off, 64));        // reduce 32-lane half
        if (j == 0) smv[oo] = m;
    }
    __syncthreads();                                 // [B4] smv ready

    // ---- wave-redundant softmax: every wave computes identical
    //      max/exp/sum of smv[0..63] via shfl trees (0 barriers) ----
    const float v = smv[lane];
    float mxv = v;
#pragma unroll
    for (int off = 32; off > 0; off >>= 1)
        mxv = fmaxf(mxv, __shfl_xor(mxv, off, 64));
    const float spv = __expf(v - mxv);
    float sumv = spv;
#pragma unroll
    for (int off = 32; off > 0; off >>= 1)
        sumv += __shfl_xor(sumv, off, 64);

    // ---- weighted E2 pooling (f32); weights fetched lane->lane via shfl ----
    float a0 = 0.f, a1 = 0.f;
#pragma unroll
    for (int it = 0; it < 4; ++it) {
        const int oo = it * 16 + h;
        const float wgt = __shfl(spv, oo, 64);
        a0 = fmaf(wgt, E2s[oo * 64 + j], a0);
        a1 = fmaf(wgt, E2s[oo * 64 + 32 + j], a1);
    }
    sred[h * 64 + j]      = a0;
    sred[h * 64 + j + 32] = a1;
    __syncthreads();                                 // [B5] sred ready
    if (tid < 64) {
        float rr = 0.f;
#pragma unroll
        for (int hh = 0; hh < 16; ++hh) rr += sred[hh * 64 + tid];
        float* dst = pool + (size_t)blockIdx.x * 68;
        dst[tid] = rr;
        if (tid == 0) { dst[64] = mxv; dst[65] = sumv; }
    }
}

// ---------------------------------------------------------------------------
// K6: combine 32 chunk-partials per b with online-softmax rescale + head bias.
// ---------------------------------------------------------------------------
__global__ void k6_final(const float* __restrict__ pool, const float* __restrict__ f2b,
                         float* __restrict__ out) {
    const int b = blockIdx.x;
    const int k = threadIdx.x;   // 64 threads
    float M = -1e30f;
#pragma unroll
    for (int c = 0; c < NCHUNK; ++c)
        M = fmaxf(M, pool[(size_t)(b * NCHUNK + c) * 68 + 64]);
    float tot = 0.f, num = 0.f;
#pragma unroll
    for (int c = 0; c < NCHUNK; ++c) {
        const float* pc = pool + (size_t)(b * NCHUNK + c) * 68;
        const float sc = __expf(pc[64] - M);
        tot = fmaf(sc, pc[65], tot);
        num = fmaf(sc, pc[k], num);
    }
    out[b * KK + k] = (num / tot) * (1.f / 2048.f) + f2b[k];
}

extern "C" void kernel_launch(void* const* d_in, const int* in_sizes, int n_in,
                              void* d_out, int out_size, void* d_ws, size_t ws_size,
                              hipStream_t stream) {
    const int*   x   = (const int*)d_in[0];
    const float* V   = (const float*)d_in[1];
    const float* C   = (const float*)d_in[2];
    const float* f1w = (const float*)d_in[3];
    const float* f1b = (const float*)d_in[4];
    const float* f2w = (const float*)d_in[5];
    const float* f2b = (const float*)d_in[6];
    float* out = (float*)d_out;

    float* ws = (float*)d_ws;
    ushort* Bu = (ushort*)ws;                 // 65536 ushort = 128 KB
    float* pool = ws + 32768;                 // 1024 * 68 floats

    k1_prep <<<128, 256, 0, stream>>>(C, f2w, Bu);
    k2_fused<<<BB * NCHUNK, 512, 0, stream>>>(x, V, (const uint4*)Bu, f1w, f1b, pool);
    k6_final<<<BB, 64, 0, stream>>>(pool, f2b, out);
}